// Round 2
// baseline (202.443 us; speedup 1.0000x reference)
//
#include <hip/hip_runtime.h>

typedef float f32x4 __attribute__((ext_vector_type(4)));
typedef short bf16x8 __attribute__((ext_vector_type(8)));

#define MFMA16(a, b, c) __builtin_amdgcn_mfma_f32_16x16x32_bf16((a), (b), (c), 0, 0, 0)

#define NN 4096
#define DD 256
#define SCALE 0.0625f

static __device__ __forceinline__ unsigned short f2bf(float f) {
  unsigned int u = __float_as_uint(f);
  u += 0x7FFFu + ((u >> 16) & 1u);   // round-to-nearest-even
  return (unsigned short)(u >> 16);
}

static __device__ __forceinline__ float softplusf(float x) {
  return (x > 20.f) ? x : log1pf(__expf(x));
}

// ---------------------------------------------------------------------------
// Prep: q/k transpose [B,C,N] -> [B,N,C] (+pos), cast to bf16.
// ---------------------------------------------------------------------------
__global__ __launch_bounds__(256) void prep_qk(
    const float* __restrict__ q, const float* __restrict__ k,
    const float* __restrict__ qp, const float* __restrict__ kp,
    unsigned short* __restrict__ qbf, unsigned short* __restrict__ kbf) {
  int n0 = blockIdx.x * 32, c0 = blockIdx.y * 32;
  int b = blockIdx.z & 1, which = blockIdx.z >> 1;
  const float* src = which ? k : q;
  const float* pos = which ? kp : qp;
  unsigned short* dst = which ? kbf : qbf;

  __shared__ float tile[32][33];
  int tx = threadIdx.x & 31, ty = threadIdx.x >> 5;
#pragma unroll
  for (int i = 0; i < 4; ++i) {
    int c = c0 + ty + i * 8;
    tile[ty + i * 8][tx] = src[((size_t)(b * DD + c)) * NN + n0 + tx];
  }
  __syncthreads();
#pragma unroll
  for (int i = 0; i < 4; ++i) {
    int n = n0 + ty + i * 8;
    float v = tile[tx][ty + i * 8] + pos[(size_t)n * DD + c0 + tx];
    dst[((size_t)(b * NN + n)) * DD + c0 + tx] = f2bf(v);
  }
}

// ---------------------------------------------------------------------------
// Prep: v cast (keeps [B,C,N] layout == V^T) + column sum.
// ---------------------------------------------------------------------------
__global__ __launch_bounds__(256) void prep_v(
    const float* __restrict__ src, unsigned short* __restrict__ vbf,
    float* __restrict__ colsum) {
  int row = blockIdx.x;  // b*256 + c
  const float* s = src + (size_t)row * NN;
  unsigned short* d = vbf + (size_t)row * NN;
  int tid = threadIdx.x;
  float sum = 0.f;
#pragma unroll
  for (int i = 0; i < 16; ++i) {
    int n = tid + i * 256;
    float v = s[n];
    sum += v;
    d[n] = f2bf(v);
  }
#pragma unroll
  for (int off = 1; off < 64; off <<= 1) sum += __shfl_xor(sum, off);
  __shared__ float ps[4];
  if ((tid & 63) == 0) ps[tid >> 6] = sum;
  __syncthreads();
  if (tid == 0) colsum[row] = ps[0] + ps[1] + ps[2] + ps[3];
}

// ---------------------------------------------------------------------------
// Prep: mask_map scalars (sum of squares of nearest-resized mask).
// ---------------------------------------------------------------------------
__global__ __launch_bounds__(256) void prep_mask(
    const float* __restrict__ me, const float* __restrict__ mm,
    float* __restrict__ msums) {
  int b = blockIdx.x >> 1, which = blockIdx.x & 1;
  const float* m = which ? mm : me;
  int tid = threadIdx.x;
  float sum = 0.f;
#pragma unroll
  for (int i = 0; i < 16; ++i) {
    int p = tid + i * 256;
    int y = p >> 6, x = p & 63;
    float v = m[(size_t)(b * 128 + 2 * y) * 128 + 2 * x];
    sum += v * v;
  }
#pragma unroll
  for (int off = 1; off < 64; off <<= 1) sum += __shfl_xor(sum, off);
  __shared__ float ps[4];
  if ((tid & 63) == 0) ps[tid >> 6] = sum;
  __syncthreads();
  if (tid == 0) msums[blockIdx.x] = ps[0] + ps[1] + ps[2] + ps[3];
}

// ---------------------------------------------------------------------------
// Flash attention partial (split-K over the KV axis).
// grid = 256*ks blocks; bid -> (split s, batch b, q-tile qt).
// Writes unnormalized O + (m,l) stats per 32-row q-tile.
// ---------------------------------------------------------------------------
__global__ __launch_bounds__(256) void attn_partial(
    const unsigned short* __restrict__ qbf,
    const unsigned short* __restrict__ kbf,
    const unsigned short* __restrict__ vbf,
    float* __restrict__ opart, float* __restrict__ mlpart,
    int ks, int kvlen) {
  // XCD-chunked swizzle: each XCD serves a contiguous bid chunk, which
  // aligns with one (split, batch) group -> shared 512KB K/V slice in L2.
  int h = blockIdx.x;
  int bid = (h & 7) * (gridDim.x >> 3) + (h >> 3);
  int s = bid >> 8;          // split index
  int rr = bid & 255;
  int b = rr >> 7;
  int qbase = (rr & 127) * 32;
  int kv0 = s * kvlen;

  int tid = threadIdx.x;
  int wid = tid >> 6;
  int lane = tid & 63;
  int lg = lane >> 4;
  int ll = lane & 15;

  __shared__ float S_lds[32][65];
  __shared__ __align__(16) unsigned short P_lds[32][72];
  __shared__ float m_st[32], l_st[32], sc_st[32];

  if (tid < 32) { m_st[tid] = -1e30f; l_st[tid] = 0.f; }

  bf16x8 qf[2][8];
  {
    const unsigned short* qb = qbf + (size_t)(b * NN + qbase) * DD;
#pragma unroll
    for (int m = 0; m < 2; ++m)
#pragma unroll
      for (int ksl = 0; ksl < 8; ++ksl)
        qf[m][ksl] = *(const bf16x8*)(qb + (size_t)(m * 16 + ll) * DD + ksl * 32 + lg * 8);
  }

  f32x4 o[2][4];
#pragma unroll
  for (int m = 0; m < 2; ++m)
#pragma unroll
    for (int c = 0; c < 4; ++c) o[m][c] = (f32x4){0.f, 0.f, 0.f, 0.f};

  const unsigned short* kb = kbf + (size_t)b * NN * DD;
  const unsigned short* vb = vbf + (size_t)b * DD * NN;

  __syncthreads();

  for (int kvb = kv0; kvb < kv0 + kvlen; kvb += 64) {
    // ---- S = Q K^T
    f32x4 s0 = (f32x4){0.f, 0.f, 0.f, 0.f};
    f32x4 s1 = (f32x4){0.f, 0.f, 0.f, 0.f};
    const unsigned short* krow = kb + (size_t)(kvb + wid * 16 + ll) * DD;
#pragma unroll
    for (int ksl = 0; ksl < 8; ++ksl) {
      bf16x8 kf = *(const bf16x8*)(krow + ksl * 32 + lg * 8);
      s0 = MFMA16(qf[0][ksl], kf, s0);
      s1 = MFMA16(qf[1][ksl], kf, s1);
    }
#pragma unroll
    for (int r = 0; r < 4; ++r) {
      S_lds[lg * 4 + r][wid * 16 + ll] = s0[r] * SCALE;
      S_lds[16 + lg * 4 + r][wid * 16 + ll] = s1[r] * SCALE;
    }
    __syncthreads();

    // ---- online softmax: 8 threads per row
    {
      int row = tid >> 3, idx = tid & 7;
      float v[8];
      float lm = -1e30f;
#pragma unroll
      for (int c = 0; c < 8; ++c) { v[c] = S_lds[row][idx * 8 + c]; lm = fmaxf(lm, v[c]); }
#pragma unroll
      for (int off = 1; off < 8; off <<= 1) lm = fmaxf(lm, __shfl_xor(lm, off, 8));
      float mo = m_st[row];
      float mn = fmaxf(mo, lm);
      float sum = 0.f;
      bf16x8 pv;
#pragma unroll
      for (int c = 0; c < 8; ++c) {
        float p = __expf(v[c] - mn);
        sum += p;
        pv[c] = (short)f2bf(p);
      }
      *(bf16x8*)(&P_lds[row][idx * 8]) = pv;
#pragma unroll
      for (int off = 1; off < 8; off <<= 1) sum += __shfl_xor(sum, off, 8);
      if (idx == 0) {
        float sc = __expf(mo - mn);
        l_st[row] = l_st[row] * sc + sum;
        m_st[row] = mn;
        sc_st[row] = sc;
      }
    }
    __syncthreads();

    // ---- rescale O
#pragma unroll
    for (int m = 0; m < 2; ++m)
#pragma unroll
      for (int r = 0; r < 4; ++r) {
        float sc = sc_st[m * 16 + lg * 4 + r];
#pragma unroll
        for (int c = 0; c < 4; ++c) o[m][c][r] *= sc;
      }

    // ---- O += P V
    bf16x8 pa[2][2];
#pragma unroll
    for (int m = 0; m < 2; ++m)
#pragma unroll
      for (int ksl = 0; ksl < 2; ++ksl)
        pa[m][ksl] = *(const bf16x8*)(&P_lds[m * 16 + ll][ksl * 32 + lg * 8]);
#pragma unroll
    for (int ct = 0; ct < 4; ++ct) {
      const unsigned short* vrow = vb + (size_t)(wid * 64 + ct * 16 + ll) * NN + kvb;
#pragma unroll
      for (int ksl = 0; ksl < 2; ++ksl) {
        bf16x8 vf = *(const bf16x8*)(vrow + ksl * 32 + lg * 8);
        o[0][ct] = MFMA16(pa[0][ksl], vf, o[0][ct]);
        o[1][ct] = MFMA16(pa[1][ksl], vf, o[1][ct]);
      }
    }
  }

  // epilogue: dump unnormalized O + stats
  size_t base = ((size_t)(b * 128) + (qbase >> 5)) * ks + s;
  base *= 32;
  float* op = opart + base * 256;
#pragma unroll
  for (int m = 0; m < 2; ++m)
#pragma unroll
    for (int r = 0; r < 4; ++r) {
      int qrow = m * 16 + lg * 4 + r;
#pragma unroll
      for (int ct = 0; ct < 4; ++ct) {
        int c = wid * 64 + ct * 16 + ll;
        op[(size_t)qrow * 256 + c] = o[m][ct][r];
      }
    }
  if (tid < 32) {
    mlpart[(base + tid) * 2 + 0] = m_st[tid];
    mlpart[(base + tid) * 2 + 1] = l_st[tid];
  }
}

// ---------------------------------------------------------------------------
// Combine: merge ks partials, normalize, add softplus-bias * colsum,
// write transposed output. grid 256 = (b, q-tile).
// ---------------------------------------------------------------------------
__global__ __launch_bounds__(256) void attn_combine(
    const float* __restrict__ opart, const float* __restrict__ mlpart,
    const float* __restrict__ colsum, const float* __restrict__ msums,
    const float* __restrict__ bias_eye, const float* __restrict__ bias_mouth,
    float* __restrict__ out, int ks) {
  int bid = blockIdx.x;
  int b = bid >> 7;
  int qbase = (bid & 127) * 32;
  int tid = threadIdx.x;

  __shared__ float m_sh[4][32], l_sh[4][32];
  __shared__ float o_sh[32][257];

  size_t base = ((size_t)bid) * ks * 32;
  if (tid < ks * 32) {
    int ss = tid >> 5, r = tid & 31;
    m_sh[ss][r] = mlpart[(base + ss * 32 + r) * 2 + 0];
    l_sh[ss][r] = mlpart[(base + ss * 32 + r) * 2 + 1];
  }
  __syncthreads();

  float sb = softplusf(bias_eye[0] * msums[b * 2 + 0]) +
             softplusf(bias_mouth[0] * msums[b * 2 + 1]);
  float cs = colsum[b * DD + tid];

  for (int r = 0; r < 32; ++r) {
    float M = m_sh[0][r];
    for (int s = 1; s < ks; ++s) M = fmaxf(M, m_sh[s][r]);
    float L = 0.f, acc = 0.f;
    for (int s = 0; s < ks; ++s) {
      float w = __expf(m_sh[s][r] - M);
      L += l_sh[s][r] * w;
      acc += w * opart[(base + s * 32 + r) * 256 + tid];
    }
    o_sh[r][tid] = acc / L + sb * cs;
  }
  __syncthreads();

  int q32 = tid & 31, ch = tid >> 5;
#pragma unroll
  for (int cc = 0; cc < 32; ++cc) {
    int c = ch * 32 + cc;
    out[((size_t)(b * DD + c)) * NN + qbase + q32] = o_sh[q32][c];
  }
}

// ---------------------------------------------------------------------------
// Fallback direct kernel (round-1 version) when ws is too small for split-K.
// ---------------------------------------------------------------------------
__global__ __launch_bounds__(256) void attn_kernel(
    const unsigned short* __restrict__ qbf,
    const unsigned short* __restrict__ kbf,
    const unsigned short* __restrict__ vbf,
    const float* __restrict__ colsum,
    const float* __restrict__ msums,
    const float* __restrict__ bias_eye,
    const float* __restrict__ bias_mouth,
    float* __restrict__ out) {
  int h = blockIdx.x;
  int bid = (h & 7) * 32 + (h >> 3);
  int b = bid >> 7;
  int qbase = (bid & 127) * 32;

  int tid = threadIdx.x;
  int wid = tid >> 6;
  int lane = tid & 63;
  int lg = lane >> 4;
  int ll = lane & 15;

  __shared__ float S_lds[32][65];
  __shared__ __align__(16) unsigned short P_lds[32][72];
  __shared__ float m_st[32], l_st[32], sc_st[32];

  if (tid < 32) { m_st[tid] = -1e30f; l_st[tid] = 0.f; }

  bf16x8 qf[2][8];
  {
    const unsigned short* qb = qbf + (size_t)(b * NN + qbase) * DD;
#pragma unroll
    for (int m = 0; m < 2; ++m)
#pragma unroll
      for (int ks = 0; ks < 8; ++ks)
        qf[m][ks] = *(const bf16x8*)(qb + (size_t)(m * 16 + ll) * DD + ks * 32 + lg * 8);
  }

  f32x4 o[2][4];
#pragma unroll
  for (int m = 0; m < 2; ++m)
#pragma unroll
    for (int c = 0; c < 4; ++c) o[m][c] = (f32x4){0.f, 0.f, 0.f, 0.f};

  const unsigned short* kb = kbf + (size_t)b * NN * DD;
  const unsigned short* vb = vbf + (size_t)b * DD * NN;

  __syncthreads();

  for (int kvb = 0; kvb < NN; kvb += 64) {
    f32x4 s0 = (f32x4){0.f, 0.f, 0.f, 0.f};
    f32x4 s1 = (f32x4){0.f, 0.f, 0.f, 0.f};
    const unsigned short* krow = kb + (size_t)(kvb + wid * 16 + ll) * DD;
#pragma unroll
    for (int ks = 0; ks < 8; ++ks) {
      bf16x8 kf = *(const bf16x8*)(krow + ks * 32 + lg * 8);
      s0 = MFMA16(qf[0][ks], kf, s0);
      s1 = MFMA16(qf[1][ks], kf, s1);
    }
#pragma unroll
    for (int r = 0; r < 4; ++r) {
      S_lds[lg * 4 + r][wid * 16 + ll] = s0[r] * SCALE;
      S_lds[16 + lg * 4 + r][wid * 16 + ll] = s1[r] * SCALE;
    }
    __syncthreads();

    {
      int row = tid >> 3, idx = tid & 7;
      float v[8];
      float lm = -1e30f;
#pragma unroll
      for (int c = 0; c < 8; ++c) { v[c] = S_lds[row][idx * 8 + c]; lm = fmaxf(lm, v[c]); }
#pragma unroll
      for (int off = 1; off < 8; off <<= 1) lm = fmaxf(lm, __shfl_xor(lm, off, 8));
      float mo = m_st[row];
      float mn = fmaxf(mo, lm);
      float sum = 0.f;
      bf16x8 pv;
#pragma unroll
      for (int c = 0; c < 8; ++c) {
        float p = __expf(v[c] - mn);
        sum += p;
        pv[c] = (short)f2bf(p);
      }
      *(bf16x8*)(&P_lds[row][idx * 8]) = pv;
#pragma unroll
      for (int off = 1; off < 8; off <<= 1) sum += __shfl_xor(sum, off, 8);
      if (idx == 0) {
        float sc = __expf(mo - mn);
        l_st[row] = l_st[row] * sc + sum;
        m_st[row] = mn;
        sc_st[row] = sc;
      }
    }
    __syncthreads();

#pragma unroll
    for (int m = 0; m < 2; ++m)
#pragma unroll
      for (int r = 0; r < 4; ++r) {
        float sc = sc_st[m * 16 + lg * 4 + r];
#pragma unroll
        for (int c = 0; c < 4; ++c) o[m][c][r] *= sc;
      }

    bf16x8 pa[2][2];
#pragma unroll
    for (int m = 0; m < 2; ++m)
#pragma unroll
      for (int ks = 0; ks < 2; ++ks)
        pa[m][ks] = *(const bf16x8*)(&P_lds[m * 16 + ll][ks * 32 + lg * 8]);
#pragma unroll
    for (int ct = 0; ct < 4; ++ct) {
      const unsigned short* vrow = vb + (size_t)(wid * 64 + ct * 16 + ll) * NN + kvb;
#pragma unroll
      for (int ks = 0; ks < 2; ++ks) {
        bf16x8 vf = *(const bf16x8*)(vrow + ks * 32 + lg * 8);
        o[0][ct] = MFMA16(pa[0][ks], vf, o[0][ct]);
        o[1][ct] = MFMA16(pa[1][ks], vf, o[1][ct]);
      }
    }
  }

  float sb = softplusf(bias_eye[0] * msums[b * 2 + 0]) +
             softplusf(bias_mouth[0] * msums[b * 2 + 1]);
#pragma unroll
  for (int m = 0; m < 2; ++m)
#pragma unroll
    for (int r = 0; r < 4; ++r) {
      int qrow = m * 16 + lg * 4 + r;
      float invl = 1.f / l_st[qrow];
      size_t qg = qbase + qrow;
#pragma unroll
      for (int ct = 0; ct < 4; ++ct) {
        int c = wid * 64 + ct * 16 + ll;
        out[((size_t)b * DD + c) * NN + qg] = o[m][ct][r] * invl + sb * colsum[b * DD + c];
      }
    }
}

// ---------------------------------------------------------------------------
extern "C" void kernel_launch(void* const* d_in, const int* in_sizes, int n_in,
                              void* d_out, int out_size, void* d_ws, size_t ws_size,
                              hipStream_t stream) {
  const float* queries    = (const float*)d_in[0];
  const float* keys       = (const float*)d_in[1];
  const float* values     = (const float*)d_in[2];
  const float* mask_eye   = (const float*)d_in[3];
  const float* mask_mouth = (const float*)d_in[4];
  const float* q_pos      = (const float*)d_in[5];
  const float* k_pos      = (const float*)d_in[6];
  const float* bias_eye   = (const float*)d_in[7];
  const float* bias_mouth = (const float*)d_in[8];
  float* out = (float*)d_out;

  char* w = (char*)d_ws;
  unsigned short* qbf = (unsigned short*)(w);                    // 4 MB
  unsigned short* kbf = (unsigned short*)(w + (4u << 20));       // 4 MB
  unsigned short* vbf = (unsigned short*)(w + (8u << 20));       // 4 MB
  float* colsum = (float*)(w + (12u << 20));                     // 2 KB
  float* msums  = (float*)(w + (12u << 20) + 4096);              // 16 B

  const size_t opart_off = (size_t)13 << 20;
  const size_t opart_chunk = (size_t)8 << 20;     // per split: 2*128*32*256*4
  const size_t ml_chunk = 65536;                  // per split: 2*128*32*2*4

  int ks = 0;
  for (int cand = 4; cand >= 1; cand >>= 1) {
    if (ws_size >= opart_off + (size_t)cand * (opart_chunk + ml_chunk)) { ks = cand; break; }
  }

  prep_qk<<<dim3(128, 8, 4), 256, 0, stream>>>(queries, keys, q_pos, k_pos, qbf, kbf);
  prep_v<<<512, 256, 0, stream>>>(values, vbf, colsum);
  prep_mask<<<4, 256, 0, stream>>>(mask_eye, mask_mouth, msums);

  if (ks > 0) {
    float* opart  = (float*)(w + opart_off);
    float* mlpart = (float*)(w + opart_off + (size_t)ks * opart_chunk);
    attn_partial<<<256 * ks, 256, 0, stream>>>(qbf, kbf, vbf, opart, mlpart,
                                               ks, NN / ks);
    attn_combine<<<256, 256, 0, stream>>>(opart, mlpart, colsum, msums,
                                          bias_eye, bias_mouth, out, ks);
  } else {
    attn_kernel<<<256, 256, 0, stream>>>(qbf, kbf, vbf, colsum, msums,
                                         bias_eye, bias_mouth, out);
  }
}

// Round 4
// 147.404 us; speedup vs baseline: 1.3734x; 1.3734x over previous
//
#include <hip/hip_runtime.h>

typedef float f32x4 __attribute__((ext_vector_type(4)));
typedef int   i32x4 __attribute__((ext_vector_type(4)));
typedef short bf16x8 __attribute__((ext_vector_type(8)));

#define MFMA16(a, b, c) __builtin_amdgcn_mfma_f32_16x16x32_bf16((a), (b), (c), 0, 0, 0)

#define NN 4096
#define DD 256
#define SCALE 0.0625f
#define THR 8.0f

static __device__ __forceinline__ unsigned short f2bf(float f) {
  unsigned int u = __float_as_uint(f);
  u += 0x7FFFu + ((u >> 16) & 1u);   // round-to-nearest-even
  return (unsigned short)(u >> 16);
}

static __device__ __forceinline__ unsigned pack2bf(float lo, float hi) {
  return (unsigned)f2bf(lo) | ((unsigned)f2bf(hi) << 16);
}

static __device__ __forceinline__ float softplusf(float x) {
  return (x > 20.f) ? x : log1pf(__expf(x));
}

// ---------------------------------------------------------------------------
// Prep: q/k transpose [B,C,N] -> [B,N,C] (+pos), cast bf16; q pre-scaled.
// ---------------------------------------------------------------------------
__global__ __launch_bounds__(256) void prep_qk(
    const float* __restrict__ q, const float* __restrict__ k,
    const float* __restrict__ qp, const float* __restrict__ kp,
    unsigned short* __restrict__ qbf, unsigned short* __restrict__ kbf) {
  int n0 = blockIdx.x * 32, c0 = blockIdx.y * 32;
  int b = blockIdx.z & 1, which = blockIdx.z >> 1;
  const float* src = which ? k : q;
  const float* pos = which ? kp : qp;
  unsigned short* dst = which ? kbf : qbf;
  float scl = which ? 1.0f : SCALE;

  __shared__ float tile[32][33];
  int tx = threadIdx.x & 31, ty = threadIdx.x >> 5;
#pragma unroll
  for (int i = 0; i < 4; ++i) {
    int c = c0 + ty + i * 8;
    tile[ty + i * 8][tx] = src[((size_t)(b * DD + c)) * NN + n0 + tx];
  }
  __syncthreads();
#pragma unroll
  for (int i = 0; i < 4; ++i) {
    int n = n0 + ty + i * 8;
    float v = (tile[tx][ty + i * 8] + pos[(size_t)n * DD + c0 + tx]) * scl;
    dst[((size_t)(b * NN + n)) * DD + c0 + tx] = f2bf(v);
  }
}

// ---------------------------------------------------------------------------
// Prep: v cast (keeps [B,C,N] layout == V^T) + column sum.
// ---------------------------------------------------------------------------
__global__ __launch_bounds__(256) void prep_v(
    const float* __restrict__ src, unsigned short* __restrict__ vbf,
    float* __restrict__ colsum) {
  int row = blockIdx.x;  // b*256 + c
  const float* s = src + (size_t)row * NN;
  unsigned short* d = vbf + (size_t)row * NN;
  int tid = threadIdx.x;
  float sum = 0.f;
#pragma unroll
  for (int i = 0; i < 16; ++i) {
    int n = tid + i * 256;
    float v = s[n];
    sum += v;
    d[n] = f2bf(v);
  }
#pragma unroll
  for (int off = 1; off < 64; off <<= 1) sum += __shfl_xor(sum, off);
  __shared__ float ps[4];
  if ((tid & 63) == 0) ps[tid >> 6] = sum;
  __syncthreads();
  if (tid == 0) colsum[row] = ps[0] + ps[1] + ps[2] + ps[3];
}

// ---------------------------------------------------------------------------
// Prep: mask_map scalars (sum of squares of nearest-resized mask).
// ---------------------------------------------------------------------------
__global__ __launch_bounds__(256) void prep_mask(
    const float* __restrict__ me, const float* __restrict__ mm,
    float* __restrict__ msums) {
  int b = blockIdx.x >> 1, which = blockIdx.x & 1;
  const float* m = which ? mm : me;
  int tid = threadIdx.x;
  float sum = 0.f;
#pragma unroll
  for (int i = 0; i < 16; ++i) {
    int p = tid + i * 256;
    int y = p >> 6, x = p & 63;
    float v = m[(size_t)(b * 128 + 2 * y) * 128 + 2 * x];
    sum += v * v;
  }
#pragma unroll
  for (int off = 1; off < 64; off <<= 1) sum += __shfl_xor(sum, off);
  __shared__ float ps[4];
  if ((tid & 63) == 0) ps[tid >> 6] = sum;
  __syncthreads();
  if (tid == 0) msums[blockIdx.x] = ps[0] + ps[1] + ps[2] + ps[3];
}

// ---------------------------------------------------------------------------
// Register-staged K/V tile path (proven mechanisms: global vec loads +
// swizzled ds_write_b128). K tile [32 kv][256 c] chunks^=row&7;
// V tile [256 d][32 kv] chunks^=(d>>1)&3. Read side applies same XOR.
// ---------------------------------------------------------------------------
struct StageRegs {
  i32x4 kr[4];
  i32x4 vr[4];
};

static __device__ __forceinline__ void load_tiles(
    const unsigned short* __restrict__ kb, const unsigned short* __restrict__ vb,
    int kvb, int wid, int lane, StageRegs& r) {
  int krow = wid * 8 + (lane >> 3);          // kv row 0..31
  int kc = lane & 7;                          // chunk low bits
  const unsigned short* kp = kb + (size_t)(kvb + krow) * DD;
#pragma unroll
  for (int i = 0; i < 4; ++i)
    r.kr[i] = *(const i32x4*)(kp + ((kc | (i << 3)) << 3));
  int vd = wid * 64 + lane;                   // d row 0..255
  const unsigned short* vp = vb + (size_t)vd * NN + kvb;
#pragma unroll
  for (int i = 0; i < 4; ++i)
    r.vr[i] = *(const i32x4*)(vp + (i << 3));
}

static __device__ __forceinline__ void write_tiles(
    char* kdst, char* vdst, int wid, int lane, const StageRegs& r) {
  int krow = wid * 8 + (lane >> 3);
  int kc = lane & 7;
  int rx = krow & 7;
#pragma unroll
  for (int i = 0; i < 4; ++i)
    *(i32x4*)(kdst + krow * 512 + (((kc | (i << 3)) ^ rx) << 4)) = r.kr[i];
  int vd = wid * 64 + lane;
  int vx = (vd >> 1) & 3;
#pragma unroll
  for (int i = 0; i < 4; ++i)
    *(i32x4*)(vdst + vd * 64 + ((i ^ vx) << 4)) = r.vr[i];
}

// ---------------------------------------------------------------------------
// Flash attention partial, swapped-QK^T, in-register softmax.
// 4 waves/block, each wave: 32 q-rows x full D=256 over its KV slice.
// One barrier per 32-kv step (double-buffered LDS tiles).
// ---------------------------------------------------------------------------
__global__ __launch_bounds__(256, 1) void attn_partial(
    const unsigned short* __restrict__ qbf,
    const unsigned short* __restrict__ kbf,
    const unsigned short* __restrict__ vbf,
    float* __restrict__ opart, float* __restrict__ mlpart, int ks) {
  // XCD-chunked swizzle: one (b,s) K/V slice per XCD chunk.
  int hwb = blockIdx.x;
  int bid = (hwb & 7) * ((int)gridDim.x >> 3) + (hwb >> 3);
  int combo = bid >> 5;          // (b, s)
  int qtg = bid & 31;
  int b = combo / ks, sidx = combo % ks;
  int kvlen = NN / ks;
  int kv0 = sidx * kvlen;
  int nt = kvlen >> 5;

  int tid = threadIdx.x, wid = tid >> 6, lane = tid & 63;
  int ll = lane & 15, lg = lane >> 4;
  int qt32 = qtg * 4 + wid;      // this wave's 32-row q tile (0..127)

  __shared__ __align__(16) unsigned short Klds[2][32 * 256];
  __shared__ __align__(16) unsigned short Vlds[2][256 * 32];

  const unsigned short* kb = kbf + (size_t)b * NN * DD;
  const unsigned short* vb = vbf + (size_t)b * DD * NN;

  // Q B-fragments: col=ll -> q = h*16+ll, k = kd*32 + lg*8 + j  (SCALE folded)
  bf16x8 qB[2][8];
  {
    const unsigned short* qp0 = qbf + ((size_t)b * NN + (size_t)qt32 * 32) * DD;
#pragma unroll
    for (int h = 0; h < 2; ++h)
#pragma unroll
      for (int kd = 0; kd < 8; ++kd)
        qB[h][kd] = *(const bf16x8*)(qp0 + (size_t)(h * 16 + ll) * DD + kd * 32 + lg * 8);
  }

  f32x4 o[2][16];
#pragma unroll
  for (int h = 0; h < 2; ++h)
#pragma unroll
    for (int db = 0; db < 16; ++db) o[h][db] = (f32x4){0.f, 0.f, 0.f, 0.f};
  float m_run[2] = {-1e30f, -1e30f};
  float l_run[2] = {0.f, 0.f};

  StageRegs sreg;
  load_tiles(kb, vb, kv0, wid, lane, sreg);
  write_tiles((char*)&Klds[0][0], (char*)&Vlds[0][0], wid, lane, sreg);
  __syncthreads();

  int buf = 0;
  for (int tt = 0; tt < nt; ++tt) {
    bool more = (tt + 1 < nt);
    if (more) load_tiles(kb, vb, kv0 + (tt + 1) * 32, wid, lane, sreg);

    const unsigned short* Kc = &Klds[buf][0];
    const unsigned short* Vc = &Vlds[buf][0];

    // ---- S^T = K Q^T : per lane, col q = h*16+ll, rows kv = 16t + lg*4 + r
    f32x4 st[2][2];
    st[0][0] = (f32x4){0.f, 0.f, 0.f, 0.f};
    st[0][1] = (f32x4){0.f, 0.f, 0.f, 0.f};
    st[1][0] = (f32x4){0.f, 0.f, 0.f, 0.f};
    st[1][1] = (f32x4){0.f, 0.f, 0.f, 0.f};
#pragma unroll
    for (int t = 0; t < 2; ++t) {
      int row = t * 16 + ll;
      int rx = row & 7;
      const unsigned short* kr = Kc + row * 256;
#pragma unroll
      for (int kd = 0; kd < 8; ++kd) {
        bf16x8 kf = *(const bf16x8*)(kr + ((((kd << 2) | lg) ^ rx) << 3));
        st[0][t] = MFMA16(kf, qB[0][kd], st[0][t]);
        st[1][t] = MFMA16(kf, qB[1][kd], st[1][t]);
      }
    }

    // ---- in-register online softmax (per lane: q = h*16 + ll)
    float tm0 = fmaxf(fmaxf(fmaxf(st[0][0][0], st[0][0][1]), fmaxf(st[0][0][2], st[0][0][3])),
                      fmaxf(fmaxf(st[0][1][0], st[0][1][1]), fmaxf(st[0][1][2], st[0][1][3])));
    float tm1 = fmaxf(fmaxf(fmaxf(st[1][0][0], st[1][0][1]), fmaxf(st[1][0][2], st[1][0][3])),
                      fmaxf(fmaxf(st[1][1][0], st[1][1][1]), fmaxf(st[1][1][2], st[1][1][3])));
    tm0 = fmaxf(tm0, __shfl_xor(tm0, 16)); tm0 = fmaxf(tm0, __shfl_xor(tm0, 32));
    tm1 = fmaxf(tm1, __shfl_xor(tm1, 16)); tm1 = fmaxf(tm1, __shfl_xor(tm1, 32));

    if (__any((tm0 > m_run[0] + THR) || (tm1 > m_run[1] + THR))) {
      float mn0 = fmaxf(m_run[0], tm0), mn1 = fmaxf(m_run[1], tm1);
      float sc0 = __expf(m_run[0] - mn0), sc1 = __expf(m_run[1] - mn1);
      l_run[0] *= sc0; l_run[1] *= sc1;
      m_run[0] = mn0; m_run[1] = mn1;
      // O rows live in q = h*16 + lg*4 + r space: fetch that row's factor
#pragma unroll
      for (int r = 0; r < 4; ++r) {
        float s0v = __shfl(sc0, (lg << 2) + r);
        float s1v = __shfl(sc1, (lg << 2) + r);
#pragma unroll
        for (int db = 0; db < 16; ++db) { o[0][db][r] *= s0v; o[1][db][r] *= s1v; }
      }
    }

    // ---- P = exp(S - m), bf16-packed; row sums
    unsigned pk0[2][2], pk1[2][2];
    float sum0 = 0.f, sum1 = 0.f;
#pragma unroll
    for (int t = 0; t < 2; ++t) {
      float a0 = __expf(st[0][t][0] - m_run[0]);
      float a1 = __expf(st[0][t][1] - m_run[0]);
      float a2 = __expf(st[0][t][2] - m_run[0]);
      float a3 = __expf(st[0][t][3] - m_run[0]);
      sum0 += (a0 + a1) + (a2 + a3);
      pk0[t][0] = pack2bf(a0, a1); pk0[t][1] = pack2bf(a2, a3);
      float b0 = __expf(st[1][t][0] - m_run[1]);
      float b1 = __expf(st[1][t][1] - m_run[1]);
      float b2 = __expf(st[1][t][2] - m_run[1]);
      float b3 = __expf(st[1][t][3] - m_run[1]);
      sum1 += (b0 + b1) + (b2 + b3);
      pk1[t][0] = pack2bf(b0, b1); pk1[t][1] = pack2bf(b2, b3);
    }
    sum0 += __shfl_xor(sum0, 16); sum0 += __shfl_xor(sum0, 32); l_run[0] += sum0;
    sum1 += __shfl_xor(sum1, 16); sum1 += __shfl_xor(sum1, 32); l_run[1] += sum1;

    // ---- redistribute P to PV A-fragments: row=ll=q, k = lg*8+j (kv)
    int srcA = ((lg & 1) << 5) + ll;
    int srcB = srcA + 16;
    bool hi = (lg >= 2);
    int a00 = __shfl((int)pk0[0][0], srcA), a01 = __shfl((int)pk0[0][1], srcA);
    int a02 = __shfl((int)pk0[0][0], srcB), a03 = __shfl((int)pk0[0][1], srcB);
    int a10 = __shfl((int)pk0[1][0], srcA), a11 = __shfl((int)pk0[1][1], srcA);
    int a12 = __shfl((int)pk0[1][0], srcB), a13 = __shfl((int)pk0[1][1], srcB);
    i32x4 fi0 = (i32x4){hi ? a10 : a00, hi ? a11 : a01, hi ? a12 : a02, hi ? a13 : a03};
    bf16x8 pa0 = __builtin_bit_cast(bf16x8, fi0);
    int c00 = __shfl((int)pk1[0][0], srcA), c01 = __shfl((int)pk1[0][1], srcA);
    int c02 = __shfl((int)pk1[0][0], srcB), c03 = __shfl((int)pk1[0][1], srcB);
    int c10 = __shfl((int)pk1[1][0], srcA), c11 = __shfl((int)pk1[1][1], srcA);
    int c12 = __shfl((int)pk1[1][0], srcB), c13 = __shfl((int)pk1[1][1], srcB);
    i32x4 fi1 = (i32x4){hi ? c10 : c00, hi ? c11 : c01, hi ? c12 : c02, hi ? c13 : c03};
    bf16x8 pa1 = __builtin_bit_cast(bf16x8, fi1);

    // ---- O += P V  (B-frag: col=ll -> d = db*16+ll, k = kv)
#pragma unroll
    for (int db = 0; db < 16; ++db) {
      int d = (db << 4) + ll;
      bf16x8 vf = *(const bf16x8*)(Vc + d * 32 + ((lg ^ ((d >> 1) & 3)) << 3));
      o[0][db] = MFMA16(pa0, vf, o[0][db]);
      o[1][db] = MFMA16(pa1, vf, o[1][db]);
    }

    if (more)
      write_tiles((char*)&Klds[buf ^ 1][0], (char*)&Vlds[buf ^ 1][0], wid, lane, sreg);
    __syncthreads();
    buf ^= 1;
  }

  // ---- epilogue: unnormalized O (layout [d][q] per slot) + (m,l) stats
  size_t slot = (size_t)(b * 128 + qt32) * ks + sidx;
  float* op = opart + slot * 8192;
#pragma unroll
  for (int h = 0; h < 2; ++h)
#pragma unroll
    for (int db = 0; db < 16; ++db)
      *(f32x4*)&op[(size_t)((db * 16 + ll) * 32 + h * 16 + lg * 4)] = o[h][db];
  if (lg == 0) {
    float* mlp = mlpart + slot * 64;
    mlp[ll * 2 + 0] = m_run[0];
    mlp[ll * 2 + 1] = l_run[0];
    mlp[(16 + ll) * 2 + 0] = m_run[1];
    mlp[(16 + ll) * 2 + 1] = l_run[1];
  }
}

// ---------------------------------------------------------------------------
// Combine: merge ks partials, normalize, add softplus-bias * colsum.
// grid 256 = (b, qt32); thread = d.
// ---------------------------------------------------------------------------
__global__ __launch_bounds__(256) void attn_combine(
    const float* __restrict__ opart, const float* __restrict__ mlpart,
    const float* __restrict__ colsum, const float* __restrict__ msums,
    const float* __restrict__ bias_eye, const float* __restrict__ bias_mouth,
    float* __restrict__ out, int ks) {
  int gb = blockIdx.x;
  int b = gb >> 7, qt32 = gb & 127;
  int tid = threadIdx.x;
  __shared__ float wtab[4][32];
  size_t slot0 = (size_t)(b * 128 + qt32) * ks;

  if (tid < 32) {
    int q = tid;
    float m[4], l[4], w[4];
    float M = -1e30f;
#pragma unroll
    for (int s = 0; s < 4; ++s) {
      if (s < ks) {
        m[s] = mlpart[(slot0 + s) * 64 + q * 2 + 0];
        l[s] = mlpart[(slot0 + s) * 64 + q * 2 + 1];
        M = fmaxf(M, m[s]);
      } else { m[s] = -1e30f; l[s] = 0.f; }
    }
    float L = 0.f;
#pragma unroll
    for (int s = 0; s < 4; ++s) {
      w[s] = (s < ks) ? __expf(m[s] - M) : 0.f;
      L += l[s] * w[s];
    }
    float invL = 1.f / L;
#pragma unroll
    for (int s = 0; s < 4; ++s) wtab[s][q] = w[s] * invL;
  }
  __syncthreads();

  int d = tid;
  float sb = softplusf(bias_eye[0] * msums[b * 2 + 0]) +
             softplusf(bias_mouth[0] * msums[b * 2 + 1]);
  float cs = colsum[b * DD + d] * sb;
  float* ob = out + ((size_t)(b * DD + d)) * NN + qt32 * 32;
#pragma unroll
  for (int g = 0; g < 8; ++g) {
    f32x4 acc = (f32x4){cs, cs, cs, cs};
#pragma unroll
    for (int s = 0; s < 4; ++s) {
      if (s < ks) {
        const f32x4 v = *(const f32x4*)&opart[(slot0 + s) * 8192 + d * 32 + g * 4];
#pragma unroll
        for (int j = 0; j < 4; ++j) acc[j] += wtab[s][g * 4 + j] * v[j];
      }
    }
    *(f32x4*)&ob[g * 4] = acc;
  }
}

// ---------------------------------------------------------------------------
extern "C" void kernel_launch(void* const* d_in, const int* in_sizes, int n_in,
                              void* d_out, int out_size, void* d_ws, size_t ws_size,
                              hipStream_t stream) {
  (void)in_sizes; (void)n_in; (void)out_size;
  const float* queries    = (const float*)d_in[0];
  const float* keys       = (const float*)d_in[1];
  const float* values     = (const float*)d_in[2];
  const float* mask_eye   = (const float*)d_in[3];
  const float* mask_mouth = (const float*)d_in[4];
  const float* q_pos      = (const float*)d_in[5];
  const float* k_pos      = (const float*)d_in[6];
  const float* bias_eye   = (const float*)d_in[7];
  const float* bias_mouth = (const float*)d_in[8];
  float* out = (float*)d_out;

  char* w = (char*)d_ws;
  unsigned short* qbf = (unsigned short*)(w);                     // 4 MB
  unsigned short* kbf = (unsigned short*)(w + ((size_t)4 << 20)); // 4 MB
  unsigned short* vbf = (unsigned short*)(w + ((size_t)8 << 20)); // 4 MB
  float* colsum = (float*)(w + ((size_t)12 << 20));               // 2 KB
  float* msums  = (float*)(w + ((size_t)12 << 20) + 4096);        // 16 B

  const size_t opart_off = (size_t)13 << 20;
  const size_t opart_chunk = (size_t)8 << 20;   // per split: 256 slots * 32KB
  const size_t ml_chunk = (size_t)65536;        // per split: 256 slots * 256B

  int ks = 1;
  for (int cand = 4; cand >= 1; cand >>= 1) {
    if (ws_size >= opart_off + (size_t)cand * (opart_chunk + ml_chunk)) { ks = cand; break; }
  }

  float* opartp = (float*)(w + opart_off);
  float* mlp    = (float*)(w + opart_off + (size_t)ks * opart_chunk);

  prep_qk<<<dim3(128, 8, 4), 256, 0, stream>>>(queries, keys, q_pos, k_pos, qbf, kbf);
  prep_v<<<512, 256, 0, stream>>>(values, vbf, colsum);
  prep_mask<<<4, 256, 0, stream>>>(mask_eye, mask_mouth, msums);

  attn_partial<<<64 * ks, 256, 0, stream>>>(qbf, kbf, vbf, opartp, mlp, ks);
  attn_combine<<<256, 256, 0, stream>>>(opartp, mlp, colsum, msums,
                                        bias_eye, bias_mouth, out, ks);
}

// Round 5
// 106.860 us; speedup vs baseline: 1.8945x; 1.3794x over previous
//
#include <hip/hip_runtime.h>

typedef float f32x4 __attribute__((ext_vector_type(4)));
typedef int   i32x4 __attribute__((ext_vector_type(4)));
typedef short bf16x8 __attribute__((ext_vector_type(8)));

#define MFMA16(a, b, c) __builtin_amdgcn_mfma_f32_16x16x32_bf16((a), (b), (c), 0, 0, 0)

#define NN 4096
#define DD 256
#define SCALE 0.0625f
#define THR 8.0f

static __device__ __forceinline__ unsigned short f2bf(float f) {
  unsigned int u = __float_as_uint(f);
  u += 0x7FFFu + ((u >> 16) & 1u);   // round-to-nearest-even
  return (unsigned short)(u >> 16);
}

static __device__ __forceinline__ unsigned pack2bf(float lo, float hi) {
  return (unsigned)f2bf(lo) | ((unsigned)f2bf(hi) << 16);
}

static __device__ __forceinline__ float softplusf(float x) {
  return (x > 20.f) ? x : log1pf(__expf(x));
}

// ---------------------------------------------------------------------------
// Prep: q/k transpose [B,C,N] -> [B,N,C] (+pos), cast bf16; q pre-scaled.
// ---------------------------------------------------------------------------
__global__ __launch_bounds__(256) void prep_qk(
    const float* __restrict__ q, const float* __restrict__ k,
    const float* __restrict__ qp, const float* __restrict__ kp,
    unsigned short* __restrict__ qbf, unsigned short* __restrict__ kbf) {
  int n0 = blockIdx.x * 32, c0 = blockIdx.y * 32;
  int b = blockIdx.z & 1, which = blockIdx.z >> 1;
  const float* src = which ? k : q;
  const float* pos = which ? kp : qp;
  unsigned short* dst = which ? kbf : qbf;
  float scl = which ? 1.0f : SCALE;

  __shared__ float tile[32][33];
  int tx = threadIdx.x & 31, ty = threadIdx.x >> 5;
#pragma unroll
  for (int i = 0; i < 4; ++i) {
    int c = c0 + ty + i * 8;
    tile[ty + i * 8][tx] = src[((size_t)(b * DD + c)) * NN + n0 + tx];
  }
  __syncthreads();
#pragma unroll
  for (int i = 0; i < 4; ++i) {
    int n = n0 + ty + i * 8;
    float v = (tile[tx][ty + i * 8] + pos[(size_t)n * DD + c0 + tx]) * scl;
    dst[((size_t)(b * NN + n)) * DD + c0 + tx] = f2bf(v);
  }
}

// ---------------------------------------------------------------------------
// Prep: v cast (keeps [B,C,N] layout == V^T) + column sum.
// ---------------------------------------------------------------------------
__global__ __launch_bounds__(256) void prep_v(
    const float* __restrict__ src, unsigned short* __restrict__ vbf,
    float* __restrict__ colsum) {
  int row = blockIdx.x;  // b*256 + c
  const float* s = src + (size_t)row * NN;
  unsigned short* d = vbf + (size_t)row * NN;
  int tid = threadIdx.x;
  float sum = 0.f;
#pragma unroll
  for (int i = 0; i < 16; ++i) {
    int n = tid + i * 256;
    float v = s[n];
    sum += v;
    d[n] = f2bf(v);
  }
#pragma unroll
  for (int off = 1; off < 64; off <<= 1) sum += __shfl_xor(sum, off);
  __shared__ float ps[4];
  if ((tid & 63) == 0) ps[tid >> 6] = sum;
  __syncthreads();
  if (tid == 0) colsum[row] = ps[0] + ps[1] + ps[2] + ps[3];
}

// ---------------------------------------------------------------------------
// Prep: mask_map scalars (sum of squares of nearest-resized mask).
// ---------------------------------------------------------------------------
__global__ __launch_bounds__(256) void prep_mask(
    const float* __restrict__ me, const float* __restrict__ mm,
    float* __restrict__ msums) {
  int b = blockIdx.x >> 1, which = blockIdx.x & 1;
  const float* m = which ? mm : me;
  int tid = threadIdx.x;
  float sum = 0.f;
#pragma unroll
  for (int i = 0; i < 16; ++i) {
    int p = tid + i * 256;
    int y = p >> 6, x = p & 63;
    float v = m[(size_t)(b * 128 + 2 * y) * 128 + 2 * x];
    sum += v * v;
  }
#pragma unroll
  for (int off = 1; off < 64; off <<= 1) sum += __shfl_xor(sum, off);
  __shared__ float ps[4];
  if ((tid & 63) == 0) ps[tid >> 6] = sum;
  __syncthreads();
  if (tid == 0) msums[blockIdx.x] = ps[0] + ps[1] + ps[2] + ps[3];
}

// ---------------------------------------------------------------------------
// Register-staged K/V tile path (proven in round 4): global vec loads +
// swizzled ds_write_b128. K tile [32 kv][256 c] chunks^=row&7;
// V tile [256 d][32 kv] chunks^=(d>>1)&3. Read side applies same XOR.
// ---------------------------------------------------------------------------
struct StageRegs {
  i32x4 kr[4];
  i32x4 vr[4];
};

static __device__ __forceinline__ void load_tiles(
    const unsigned short* __restrict__ kb, const unsigned short* __restrict__ vb,
    int kvb, int wid, int lane, StageRegs& r) {
  int krow = wid * 8 + (lane >> 3);          // kv row 0..31
  int kc = lane & 7;                          // chunk low bits
  const unsigned short* kp = kb + (size_t)(kvb + krow) * DD;
#pragma unroll
  for (int i = 0; i < 4; ++i)
    r.kr[i] = *(const i32x4*)(kp + ((kc | (i << 3)) << 3));
  int vd = wid * 64 + lane;                   // d row 0..255
  const unsigned short* vp = vb + (size_t)vd * NN + kvb;
#pragma unroll
  for (int i = 0; i < 4; ++i)
    r.vr[i] = *(const i32x4*)(vp + (i << 3));
}

static __device__ __forceinline__ void write_tiles(
    char* kdst, char* vdst, int wid, int lane, const StageRegs& r) {
  int krow = wid * 8 + (lane >> 3);
  int kc = lane & 7;
  int rx = krow & 7;
#pragma unroll
  for (int i = 0; i < 4; ++i)
    *(i32x4*)(kdst + krow * 512 + (((kc | (i << 3)) ^ rx) << 4)) = r.kr[i];
  int vd = wid * 64 + lane;
  int vx = (vd >> 1) & 3;
#pragma unroll
  for (int i = 0; i < 4; ++i)
    *(i32x4*)(vdst + vd * 64 + ((i ^ vx) << 4)) = r.vr[i];
}

// ---------------------------------------------------------------------------
// Flash attention partial, swapped-QK^T, in-register softmax.
// QBLK=16/wave, 4 waves/block (64 q-rows), KVBLK=32, grid = 2*ks*64 blocks
// -> 2 blocks/CU, 2 waves/SIMD. One barrier per 32-kv step.
// ---------------------------------------------------------------------------
__global__ __launch_bounds__(256, 2) void attn_partial(
    const unsigned short* __restrict__ qbf,
    const unsigned short* __restrict__ kbf,
    const unsigned short* __restrict__ vbf,
    float* __restrict__ opart, float* __restrict__ mlpart, int ks) {
  // XCD-chunked swizzle: one (b,s) combo (= one 1MB K/V slice) per XCD.
  int hwb = blockIdx.x;
  int bid = (hwb & 7) * ((int)gridDim.x >> 3) + (hwb >> 3);
  int combo = bid >> 6;          // (b, s)
  int qtg = bid & 63;            // 64-q group within batch
  int b = combo / ks, sidx = combo % ks;
  int kvlen = NN / ks;
  int kv0 = sidx * kvlen;
  int nt = kvlen >> 5;

  int tid = threadIdx.x, wid = tid >> 6, lane = tid & 63;
  int ll = lane & 15, lg = lane >> 4;
  int qt16 = qtg * 4 + wid;      // this wave's 16-row q tile (0..255)

  __shared__ __align__(16) unsigned short Klds[2][32 * 256];
  __shared__ __align__(16) unsigned short Vlds[2][256 * 32];

  const unsigned short* kb = kbf + (size_t)b * NN * DD;
  const unsigned short* vb = vbf + (size_t)b * DD * NN;

  // Q B-fragments: col=ll -> q = ll, k = kd*32 + lg*8 + j  (SCALE folded)
  bf16x8 qB[8];
  {
    const unsigned short* qp0 = qbf + ((size_t)b * NN + (size_t)qt16 * 16) * DD;
#pragma unroll
    for (int kd = 0; kd < 8; ++kd)
      qB[kd] = *(const bf16x8*)(qp0 + (size_t)ll * DD + kd * 32 + lg * 8);
  }

  f32x4 o[16];
#pragma unroll
  for (int db = 0; db < 16; ++db) o[db] = (f32x4){0.f, 0.f, 0.f, 0.f};
  float m_run = -1e30f;
  float l_run = 0.f;

  StageRegs sreg;
  load_tiles(kb, vb, kv0, wid, lane, sreg);
  write_tiles((char*)&Klds[0][0], (char*)&Vlds[0][0], wid, lane, sreg);
  __syncthreads();

  int buf = 0;
  for (int tt = 0; tt < nt; ++tt) {
    bool more = (tt + 1 < nt);
    if (more) load_tiles(kb, vb, kv0 + (tt + 1) * 32, wid, lane, sreg);

    const unsigned short* Kc = &Klds[buf][0];
    const unsigned short* Vc = &Vlds[buf][0];

    // ---- S^T = K Q^T : per lane, col q = ll, rows kv = 16t + lg*4 + r
    f32x4 st[2];
    st[0] = (f32x4){0.f, 0.f, 0.f, 0.f};
    st[1] = (f32x4){0.f, 0.f, 0.f, 0.f};
    __builtin_amdgcn_s_setprio(1);
#pragma unroll
    for (int t = 0; t < 2; ++t) {
      int row = t * 16 + ll;
      int rx = row & 7;
      const unsigned short* kr = Kc + row * 256;
#pragma unroll
      for (int kd = 0; kd < 8; ++kd) {
        bf16x8 kf = *(const bf16x8*)(kr + ((((kd << 2) | lg) ^ rx) << 3));
        st[t] = MFMA16(kf, qB[kd], st[t]);
      }
    }
    __builtin_amdgcn_s_setprio(0);

    // ---- in-register online softmax (per lane: q = ll)
    float tm = fmaxf(fmaxf(fmaxf(st[0][0], st[0][1]), fmaxf(st[0][2], st[0][3])),
                     fmaxf(fmaxf(st[1][0], st[1][1]), fmaxf(st[1][2], st[1][3])));
    tm = fmaxf(tm, __shfl_xor(tm, 16));
    tm = fmaxf(tm, __shfl_xor(tm, 32));

    if (__any(tm > m_run + THR)) {
      float mn = fmaxf(m_run, tm);
      float sc = __expf(m_run - mn);
      l_run *= sc;
      m_run = mn;
      // O rows live in q = lg*4 + r space: fetch that row's factor
#pragma unroll
      for (int r = 0; r < 4; ++r) {
        float sv = __shfl(sc, (lg << 2) + r);
#pragma unroll
        for (int db = 0; db < 16; ++db) o[db][r] *= sv;
      }
    }

    // ---- P = exp(S - m), bf16-packed; row sums
    unsigned pk[2][2];
    float sum = 0.f;
#pragma unroll
    for (int t = 0; t < 2; ++t) {
      float a0 = __expf(st[t][0] - m_run);
      float a1 = __expf(st[t][1] - m_run);
      float a2 = __expf(st[t][2] - m_run);
      float a3 = __expf(st[t][3] - m_run);
      sum += (a0 + a1) + (a2 + a3);
      pk[t][0] = pack2bf(a0, a1);
      pk[t][1] = pack2bf(a2, a3);
    }
    sum += __shfl_xor(sum, 16);
    sum += __shfl_xor(sum, 32);
    l_run += sum;

    // ---- redistribute P to PV A-fragment: row=ll=q, k = lg*8+j (kv)
    int srcA = ((lg & 1) << 5) + ll;
    int srcB = srcA + 16;
    bool hi = (lg >= 2);
    int a00 = __shfl((int)pk[0][0], srcA), a01 = __shfl((int)pk[0][1], srcA);
    int a02 = __shfl((int)pk[0][0], srcB), a03 = __shfl((int)pk[0][1], srcB);
    int a10 = __shfl((int)pk[1][0], srcA), a11 = __shfl((int)pk[1][1], srcA);
    int a12 = __shfl((int)pk[1][0], srcB), a13 = __shfl((int)pk[1][1], srcB);
    i32x4 fi = (i32x4){hi ? a10 : a00, hi ? a11 : a01, hi ? a12 : a02, hi ? a13 : a03};
    bf16x8 pa = __builtin_bit_cast(bf16x8, fi);

    // ---- O += P V  (B-frag: col=ll -> d = db*16+ll, k = kv)
    __builtin_amdgcn_s_setprio(1);
#pragma unroll
    for (int db = 0; db < 16; ++db) {
      int d = (db << 4) + ll;
      bf16x8 vf = *(const bf16x8*)(Vc + d * 32 + ((lg ^ ((d >> 1) & 3)) << 3));
      o[db] = MFMA16(pa, vf, o[db]);
    }
    __builtin_amdgcn_s_setprio(0);

    if (more)
      write_tiles((char*)&Klds[buf ^ 1][0], (char*)&Vlds[buf ^ 1][0], wid, lane, sreg);
    __syncthreads();
    buf ^= 1;
  }

  // ---- epilogue: unnormalized O (layout [d][q] per slot) + (m,l) stats
  size_t slot = (size_t)(b * 256 + qt16) * ks + sidx;
  float* op = opart + slot * 4096;
#pragma unroll
  for (int db = 0; db < 16; ++db)
    *(f32x4*)&op[(size_t)((db * 16 + ll) * 16 + lg * 4)] = o[db];
  if (lg == 0) {
    float* mlp = mlpart + slot * 32;
    mlp[ll * 2 + 0] = m_run;
    mlp[ll * 2 + 1] = l_run;
  }
}

// ---------------------------------------------------------------------------
// Combine: merge ks partials, normalize, add softplus-bias * colsum.
// grid 512 = (b, qt16); thread = d.
// ---------------------------------------------------------------------------
__global__ __launch_bounds__(256) void attn_combine(
    const float* __restrict__ opart, const float* __restrict__ mlpart,
    const float* __restrict__ colsum, const float* __restrict__ msums,
    const float* __restrict__ bias_eye, const float* __restrict__ bias_mouth,
    float* __restrict__ out, int ks) {
  int gb = blockIdx.x;
  int b = gb >> 8, qt16 = gb & 255;
  int tid = threadIdx.x;
  __shared__ float wtab[4][16];
  size_t slot0 = (size_t)(b * 256 + qt16) * ks;

  if (tid < 16) {
    int q = tid;
    float m[4], l[4], w[4];
    float M = -1e30f;
#pragma unroll
    for (int s = 0; s < 4; ++s) {
      if (s < ks) {
        m[s] = mlpart[(slot0 + s) * 32 + q * 2 + 0];
        l[s] = mlpart[(slot0 + s) * 32 + q * 2 + 1];
        M = fmaxf(M, m[s]);
      } else { m[s] = -1e30f; l[s] = 0.f; }
    }
    float L = 0.f;
#pragma unroll
    for (int s = 0; s < 4; ++s) {
      w[s] = (s < ks) ? __expf(m[s] - M) : 0.f;
      L += l[s] * w[s];
    }
    float invL = 1.f / L;
#pragma unroll
    for (int s = 0; s < 4; ++s) wtab[s][q] = w[s] * invL;
  }
  __syncthreads();

  int d = tid;
  float sb = softplusf(bias_eye[0] * msums[b * 2 + 0]) +
             softplusf(bias_mouth[0] * msums[b * 2 + 1]);
  float cs = colsum[b * DD + d] * sb;
  float* ob = out + ((size_t)(b * DD + d)) * NN + qt16 * 16;
#pragma unroll
  for (int g = 0; g < 4; ++g) {
    f32x4 acc = (f32x4){cs, cs, cs, cs};
#pragma unroll
    for (int s = 0; s < 4; ++s) {
      if (s < ks) {
        const f32x4 v = *(const f32x4*)&opart[(slot0 + s) * 4096 + d * 16 + g * 4];
#pragma unroll
        for (int j = 0; j < 4; ++j) acc[j] += wtab[s][g * 4 + j] * v[j];
      }
    }
    *(f32x4*)&ob[g * 4] = acc;
  }
}

// ---------------------------------------------------------------------------
extern "C" void kernel_launch(void* const* d_in, const int* in_sizes, int n_in,
                              void* d_out, int out_size, void* d_ws, size_t ws_size,
                              hipStream_t stream) {
  (void)in_sizes; (void)n_in; (void)out_size;
  const float* queries    = (const float*)d_in[0];
  const float* keys       = (const float*)d_in[1];
  const float* values     = (const float*)d_in[2];
  const float* mask_eye   = (const float*)d_in[3];
  const float* mask_mouth = (const float*)d_in[4];
  const float* q_pos      = (const float*)d_in[5];
  const float* k_pos      = (const float*)d_in[6];
  const float* bias_eye   = (const float*)d_in[7];
  const float* bias_mouth = (const float*)d_in[8];
  float* out = (float*)d_out;

  char* w = (char*)d_ws;
  unsigned short* qbf = (unsigned short*)(w);                     // 4 MB
  unsigned short* kbf = (unsigned short*)(w + ((size_t)4 << 20)); // 4 MB
  unsigned short* vbf = (unsigned short*)(w + ((size_t)8 << 20)); // 4 MB
  float* colsum = (float*)(w + ((size_t)12 << 20));               // 2 KB
  float* msums  = (float*)(w + ((size_t)12 << 20) + 4096);        // 16 B

  const size_t opart_off = (size_t)13 << 20;
  const size_t opart_chunk = (size_t)8 << 20;   // per split: 512 slots * 16KB
  const size_t ml_chunk = (size_t)65536;        // per split: 512 slots * 128B

  int ks = 1;
  for (int cand = 4; cand >= 1; cand >>= 1) {
    if (ws_size >= opart_off + (size_t)cand * (opart_chunk + ml_chunk)) { ks = cand; break; }
  }

  float* opartp = (float*)(w + opart_off);
  float* mlp    = (float*)(w + opart_off + (size_t)ks * opart_chunk);

  prep_qk<<<dim3(128, 8, 4), 256, 0, stream>>>(queries, keys, q_pos, k_pos, qbf, kbf);
  prep_v<<<512, 256, 0, stream>>>(values, vbf, colsum);
  prep_mask<<<4, 256, 0, stream>>>(mask_eye, mask_mouth, msums);

  attn_partial<<<2 * ks * 64, 256, 0, stream>>>(qbf, kbf, vbf, opartp, mlp, ks);
  attn_combine<<<512, 256, 0, stream>>>(opartp, mlp, colsum, msums,
                                        bias_eye, bias_mouth, out, ks);
}